// Round 6
// baseline (108.269 us; speedup 1.0000x reference)
//
#include <hip/hip_runtime.h>
#include <hip/hip_bf16.h>

#define NROW 4096
#define KDIM 2048
#define ROWB (KDIM * 2)     // bytes per Xb row
#define BT 256              // block tile (M = N)
#define BK 64               // k-tile depth (128 bytes)
#define NT (KDIM / BK)      // 32 k-tiles
#define LDSBUF 65536        // per k-tile: A 32 KB + B 32 KB
#define PHI(r) (((r) & 7) << 4)

typedef __attribute__((ext_vector_type(8))) short bf16x8;
typedef __attribute__((ext_vector_type(4))) float f32x4;
typedef __attribute__((ext_vector_type(4))) unsigned short u16x4;

#define MFMA16(a, b, c) __builtin_amdgcn_mfma_f32_16x16x32_bf16((a), (b), (c), 0, 0, 0)

__device__ __forceinline__ unsigned short f2bf(float x) {
    unsigned u = __float_as_uint(x);
    unsigned r = (u + 0x7FFFu + ((u >> 16) & 1u)) >> 16;
    return (unsigned short)r;
}
__device__ __forceinline__ float bf2f(unsigned short b) {
    return __uint_as_float(((unsigned)b) << 16);
}

// Kernel 1: fp32 -> bf16 copy + row sum-of-squares from the bf16 values.
__global__ __launch_bounds__(256) void k_convert(const float* __restrict__ X,
                                                 unsigned short* __restrict__ Xb,
                                                 float* __restrict__ sqv) {
    const int row = blockIdx.x;
    const int t = threadIdx.x;
    const float4* xr = (const float4*)(X + (size_t)row * KDIM);
    unsigned short* br = Xb + (size_t)row * KDIM;
    float acc = 0.f;
#pragma unroll
    for (int it = 0; it < 2; ++it) {
        int idx = t * 2 + it;
        float4 v = xr[idx];
        u16x4 b;
        b.x = f2bf(v.x); b.y = f2bf(v.y); b.z = f2bf(v.z); b.w = f2bf(v.w);
        float f0 = bf2f(b.x), f1 = bf2f(b.y), f2 = bf2f(b.z), f3 = bf2f(b.w);
        acc += f0 * f0 + f1 * f1 + f2 * f2 + f3 * f3;
        *(u16x4*)(br + idx * 4) = b;
    }
#pragma unroll
    for (int s = 32; s > 0; s >>= 1) acc += __shfl_xor(acc, s);
    __shared__ float red[4];
    const int lane = t & 63, wid = t >> 6;
    if (lane == 0) red[wid] = acc;
    __syncthreads();
    if (t == 0) sqv[row] = red[0] + red[1] + red[2] + red[3];
}

// Kernel 2: init per-row accumulators + zero the output scalar.
__global__ __launch_bounds__(256) void k_init(unsigned* hp, unsigned* hn,
                                              unsigned* mor, unsigned* mir,
                                              int* anyor, float* out) {
    int i = blockIdx.x * 256 + threadIdx.x;
    hp[i] = 0u;
    hn[i] = 0x7F800000u;
    mor[i] = 0u;
    mir[i] = 0x7F800000u;
    anyor[i] = 0;
    if (i == 0) out[0] = 0.f;
}

// Kernel 3: 256x256 Gram GEMM, BK=64, 8 waves, double-buffered LDS.
// Software-pipelined fragment reads (issued one phase before use) with
// sched_barrier(0) pins after each [stage + ds_read] cluster so the LLVM
// scheduler cannot sink the reads below the MFMA cluster (which would
// serialize the LDS and MFMA pipes). Counted vmcnt only; source-side XOR
// swizzle (rule #21).
__global__ __launch_bounds__(512, 2) void k_gemm(const unsigned short* __restrict__ Xb,
                                                 const float* __restrict__ sqv,
                                                 const int* __restrict__ ta,
                                                 const int* __restrict__ tb,
                                                 unsigned int* __restrict__ hp,
                                                 unsigned int* __restrict__ hn,
                                                 unsigned int* __restrict__ mor,
                                                 unsigned int* __restrict__ mir,
                                                 int* __restrict__ anyor) {
    __shared__ char lds[2 * LDSBUF];  // 128 KiB
    const int bi = blockIdx.x >> 4;
    const int bj = blockIdx.x & 15;
    const int t = threadIdx.x;
    const int lane = t & 63;
    const int w = t >> 6;        // wave 0..7
    const int wm = w >> 2;       // 0..1  (128-row half of A)
    const int wn = w & 3;        // 0..3  (64-col quarter of B)
    const int l15 = lane & 15;
    const int kg16 = (lane >> 4) * 16;  // k-group byte offset within 64B k-slot
    const char* xbase = (const char*)Xb;

    // ds_read bases: swizzle XOR P=(l15&7)<<4 is lane-constant; row offsets
    // become compile-time +m*2048 immediates
    const int P = (l15 & 7) << 4;
    int akb[2], bkb[2];
#pragma unroll
    for (int ks = 0; ks < 2; ++ks) {
        const int kx = (ks * 64 + kg16) ^ P;  // disjoint bits -> bitwise xor ok
        akb[ks] = (wm * 128 + l15) * 128 + kx;
        bkb[ks] = 32768 + (wn * 64 + l15) * 128 + kx;
    }

    f32x4 acc[8][4] = {};

    // stage 8 KB chunk p of k-tile tt into buf tt&1. Chunk p<4: A rows
    // p*64..p*64+63; p>=4: B rows (p-4)*64... thread t covers row t>>3,
    // 16B col t&7. LDS dest linear; swizzle on the global source.
#define STAGE(tt, p)                                                          \
    do {                                                                      \
        constexpr int isb_ = (p) >= 4;                                        \
        constexpr int c_ = (p) - isb_ * 4;                                    \
        const int row_ = c_ * 64 + (t >> 3);                                  \
        const int gr_ = (isb_ ? bj : bi) * BT + row_;                         \
        const char* gsrc_ = xbase + (size_t)gr_ * ROWB + (size_t)(tt) * 128 + \
                            (((t & 7) * 16) ^ PHI(row_));                     \
        char* ldst_ = lds + ((tt) & 1) * LDSBUF + isb_ * 32768 + row_ * 128 + \
                      (t & 7) * 16;                                           \
        __builtin_amdgcn_global_load_lds(                                     \
            (const __attribute__((address_space(1))) void*)gsrc_,             \
            (__attribute__((address_space(3))) void*)ldst_, 16, 0, 0);        \
    } while (0)

    // prologue: stage tile 0 (chunks {1,3} last), wait all but {1,3},
    // pre-read A0(0)+B01(0) so P0's MFMA has operands.
    STAGE(0, 0); STAGE(0, 2); STAGE(0, 4); STAGE(0, 5);
    STAGE(0, 6); STAGE(0, 7); STAGE(0, 1); STAGE(0, 3);
    asm volatile("s_waitcnt vmcnt(2)" ::: "memory");
    __builtin_amdgcn_s_barrier();

    bf16x8 af0[4][2], af1[4][2], b01[2][2], b23[2][2];
#pragma unroll
    for (int ks = 0; ks < 2; ++ks) {
#pragma unroll
        for (int m = 0; m < 4; ++m)
            af0[m][ks] = *(const bf16x8*)(lds + akb[ks] + m * 2048);
        b01[0][ks] = *(const bf16x8*)(lds + bkb[ks]);
        b01[1][ks] = *(const bf16x8*)(lds + bkb[ks] + 2048);
    }

    for (int tk = 0; tk < NT; ++tk) {
        const char* bufc = lds + (tk & 1) * LDSBUF;
        const char* bufn = lds + ((tk + 1) & 1) * LDSBUF;
        const bool stg = (tk + 1) < NT;

        // ---- P0: stage 6 chunks(next); read B23(cur) [for P1]; MFMA q00
        if (stg) {
            STAGE(tk + 1, 0); STAGE(tk + 1, 2); STAGE(tk + 1, 4);
            STAGE(tk + 1, 5); STAGE(tk + 1, 6); STAGE(tk + 1, 7);
        }
#pragma unroll
        for (int ks = 0; ks < 2; ++ks) {
            b23[0][ks] = *(const bf16x8*)(bufc + bkb[ks] + 2 * 2048);
            b23[1][ks] = *(const bf16x8*)(bufc + bkb[ks] + 3 * 2048);
        }
        __builtin_amdgcn_sched_barrier(0);  // pin: stage+reads ISSUE before MFMA
        __builtin_amdgcn_s_setprio(1);
#pragma unroll
        for (int ks = 0; ks < 2; ++ks)
#pragma unroll
            for (int m = 0; m < 4; ++m) {
                acc[m][0] = MFMA16(af0[m][ks], b01[0][ks], acc[m][0]);
                acc[m][1] = MFMA16(af0[m][ks], b01[1][ks], acc[m][1]);
            }
        __builtin_amdgcn_s_setprio(0);

        // ---- P1: stage {1,3}(next); vmcnt+bar; read A1(cur) [for P2]; q01
        if (stg) {
            STAGE(tk + 1, 1); STAGE(tk + 1, 3);
            asm volatile("s_waitcnt vmcnt(8)" ::: "memory");  // {1,3}(cur) in
        } else {
            asm volatile("s_waitcnt vmcnt(0)" ::: "memory");
        }
        __builtin_amdgcn_s_barrier();
#pragma unroll
        for (int ks = 0; ks < 2; ++ks)
#pragma unroll
            for (int m = 0; m < 4; ++m)
                af1[m][ks] = *(const bf16x8*)(bufc + akb[ks] + (4 + m) * 2048);
        __builtin_amdgcn_sched_barrier(0);  // pin: A1 reads issue before MFMA
        __builtin_amdgcn_s_setprio(1);
#pragma unroll
        for (int ks = 0; ks < 2; ++ks)
#pragma unroll
            for (int m = 0; m < 4; ++m) {
                acc[m][2] = MFMA16(af0[m][ks], b23[0][ks], acc[m][2]);
                acc[m][3] = MFMA16(af0[m][ks], b23[1][ks], acc[m][3]);
            }
        __builtin_amdgcn_s_setprio(0);

        // ---- P2: vmcnt(2)+bar; read A0(next) [for P0']; MFMA q12
        if (stg) {
            asm volatile("s_waitcnt vmcnt(2)" ::: "memory");  // 6 chunks(next) in
            __builtin_amdgcn_s_barrier();
#pragma unroll
            for (int ks = 0; ks < 2; ++ks)
#pragma unroll
                for (int m = 0; m < 4; ++m)
                    af0[m][ks] = *(const bf16x8*)(bufn + akb[ks] + m * 2048);
        }
        __builtin_amdgcn_sched_barrier(0);  // pin: A0(next) reads issue before MFMA
        __builtin_amdgcn_s_setprio(1);
#pragma unroll
        for (int ks = 0; ks < 2; ++ks)
#pragma unroll
            for (int m = 0; m < 4; ++m) {
                acc[4 + m][2] = MFMA16(af1[m][ks], b23[0][ks], acc[4 + m][2]);
                acc[4 + m][3] = MFMA16(af1[m][ks], b23[1][ks], acc[4 + m][3]);
            }
        __builtin_amdgcn_s_setprio(0);

        // ---- P3: MFMA q10; then read B01(next) [for P0'] (WAR on b01
        // forces read-after-MFMA here); bar
        __builtin_amdgcn_s_setprio(1);
#pragma unroll
        for (int ks = 0; ks < 2; ++ks)
#pragma unroll
            for (int m = 0; m < 4; ++m) {
                acc[4 + m][0] = MFMA16(af1[m][ks], b01[0][ks], acc[4 + m][0]);
                acc[4 + m][1] = MFMA16(af1[m][ks], b01[1][ks], acc[4 + m][1]);
            }
        __builtin_amdgcn_s_setprio(0);
        if (stg) {
#pragma unroll
            for (int ks = 0; ks < 2; ++ks) {
                b01[0][ks] = *(const bf16x8*)(bufn + bkb[ks]);
                b01[1][ks] = *(const bf16x8*)(bufn + bkb[ks] + 2048);
            }
        }
        __builtin_amdgcn_s_barrier();
    }
#undef STAGE

    // ---- epilogue: dist + masks + row-side reductions ----
    float sqj[4];
    int taj[4], tbj[4];
#pragma unroll
    for (int n = 0; n < 4; ++n) {
        int j = bj * BT + wn * 64 + n * 16 + l15;
        sqj[n] = sqv[j];
        taj[n] = ta[j];
        tbj[n] = tb[j];
    }
    const float INF = __uint_as_float(0x7F800000u);
#pragma unroll
    for (int m = 0; m < 8; ++m) {
#pragma unroll
        for (int reg = 0; reg < 4; ++reg) {
            const int i = bi * BT + wm * 128 + m * 16 + (lane >> 4) * 4 + reg;
            const float sqi = sqv[i];
            const int tai = ta[i], tbi = tb[i];
            float vhp = 0.f, vhn = INF, vmor = 0.f, vmir = INF, vany = 0.f;
#pragma unroll
            for (int n = 0; n < 4; ++n) {
                float d2 = sqi + sqj[n] - 2.f * acc[m][n][reg];
                float d = sqrtf(fmaxf(d2, 1e-12f));
                bool ma = (tai == taj[n]), mb = (tbi == tbj[n]);
                if (ma && mb) {
                    vhp = fmaxf(vhp, d);
                } else if (ma != mb) {
                    vmor = fmaxf(vmor, d);
                    vmir = fminf(vmir, d);
                    vany = 1.f;
                } else {
                    vhn = fminf(vhn, d);
                }
            }
#pragma unroll
            for (int s = 1; s < 16; s <<= 1) {
                vhp = fmaxf(vhp, __shfl_xor(vhp, s, 16));
                vhn = fminf(vhn, __shfl_xor(vhn, s, 16));
                vmor = fmaxf(vmor, __shfl_xor(vmor, s, 16));
                vmir = fminf(vmir, __shfl_xor(vmir, s, 16));
                vany = fmaxf(vany, __shfl_xor(vany, s, 16));
            }
            if (l15 == 0) {
                if (vhp > 0.f) atomicMax(&hp[i], __float_as_uint(vhp));
                if (vhn < INF) atomicMin(&hn[i], __float_as_uint(vhn));
                if (vany > 0.f) {
                    atomicMax(&mor[i], __float_as_uint(vmor));
                    atomicMin(&mir[i], __float_as_uint(vmir));
                    atomicOr(&anyor[i], 1);
                }
            }
        }
    }
}

// Kernel 4: final scalar loss (16 blocks, one row per thread, atomicAdd).
__global__ __launch_bounds__(256) void k_final(const unsigned* __restrict__ hp,
                                               const unsigned* __restrict__ hn,
                                               const unsigned* __restrict__ mor,
                                               const unsigned* __restrict__ mir,
                                               const int* __restrict__ anyor,
                                               const int* __restrict__ epoch_p,
                                               float* __restrict__ out) {
    const int t = threadIdx.x;
    const int i = blockIdx.x * 256 + t;
    const bool eok = (*epoch_p > 50);
    float fhp = __uint_as_float(hp[i]);
    float fhn = __uint_as_float(hn[i]);
    bool use_or = (anyor[i] != 0) && eok;
    float sp = use_or ? __uint_as_float(mor[i]) : fhp;
    float sn = use_or ? __uint_as_float(mir[i]) : fhn;
    float s = fmaxf(0.f, fhp - fhn + 0.3f) + fmaxf(0.f, sp - fhn + 0.3f) +
              fmaxf(0.f, fhp - sn + 0.3f);
#pragma unroll
    for (int sh = 32; sh > 0; sh >>= 1) s += __shfl_xor(s, sh);
    __shared__ float red[4];
    const int lane = t & 63, wid = t >> 6;
    if (lane == 0) red[wid] = s;
    __syncthreads();
    if (t == 0)
        atomicAdd(out, (red[0] + red[1] + red[2] + red[3]) * (1.f / 4096.f));
}

extern "C" void kernel_launch(void* const* d_in, const int* in_sizes, int n_in,
                              void* d_out, int out_size, void* d_ws, size_t ws_size,
                              hipStream_t stream) {
    const float* X = (const float*)d_in[0];
    const int* ta = (const int*)d_in[1];
    const int* tb = (const int*)d_in[2];
    const int* epoch_p = (const int*)d_in[4];
    float* out = (float*)d_out;

    char* ws = (char*)d_ws;
    unsigned short* Xb = (unsigned short*)ws;  // 16 MB bf16 copy
    size_t off = (size_t)NROW * KDIM * sizeof(unsigned short);
    float* sqv = (float*)(ws + off); off += (size_t)NROW * 4;
    unsigned* hp = (unsigned*)(ws + off); off += (size_t)NROW * 4;
    unsigned* hn = (unsigned*)(ws + off); off += (size_t)NROW * 4;
    unsigned* mor = (unsigned*)(ws + off); off += (size_t)NROW * 4;
    unsigned* mir = (unsigned*)(ws + off); off += (size_t)NROW * 4;
    int* anyor = (int*)(ws + off); off += (size_t)NROW * 4;

    k_convert<<<NROW, 256, 0, stream>>>(X, Xb, sqv);
    k_init<<<NROW / 256, 256, 0, stream>>>(hp, hn, mor, mir, anyor, out);
    k_gemm<<<(NROW / BT) * (NROW / BT), 512, 0, stream>>>(Xb, sqv, ta, tb,
                                                          hp, hn, mor, mir, anyor);
    k_final<<<NROW / 256, 256, 0, stream>>>(hp, hn, mor, mir, anyor, epoch_p, out);
}